// Round 5
// baseline (289.588 us; speedup 1.0000x reference)
//
#include <hip/hip_runtime.h>

#define SENS 200
#define DM 128
#define SEQ 96
#define NB 8
#define BS 768            // NB*SEQ
#define NTOT 153600       // BS*SENS
#define TH 0.01f
#define BN_EPS 1e-5f
#define MPAD 224          // padded sensor dim (7*32)
#define KP 208            // effective K for phase2 / xw cols (13*16)
#define ASROW 68          // out As stride (136 B = 34 dw, gcd 2 -> free; 8B-aligned)

typedef __attribute__((ext_vector_type(8)))  __bf16 bf16x8;
typedef __attribute__((ext_vector_type(4)))  __bf16 bf16x4;
typedef __attribute__((ext_vector_type(16))) float  f32x16;

__device__ __forceinline__ f32x16 mfma32(bf16x8 a, bf16x8 b, f32x16 c) {
    return __builtin_amdgcn_mfma_f32_32x32x16_bf16(a, b, c, 0, 0, 0);
}
__device__ __forceinline__ bf16x8 join8(bf16x4 a, bf16x4 b) {
    bf16x8 r;
    #pragma unroll
    for (int j = 0; j < 4; ++j) { r[j] = a[j]; r[j + 4] = b[j]; }
    return r;
}

// ---------------- mean over 64 attention maps ----------------
__global__ void attn_mean_kernel(const float* __restrict__ attn, float* __restrict__ mapA) {
    int idx = blockIdx.x * 256 + threadIdx.x;
    if (idx >= SENS * SENS) return;
    float s = 0.f;
    #pragma unroll 8
    for (int q = 0; q < 64; ++q) s += attn[(size_t)q * SENS * SENS + idx];
    mapA[idx] = s * (1.0f / 64.0f);
}

// ---------------- symmetrize + clamp + degree ----------------
__global__ void build_map_kernel(const float* __restrict__ supports, const float* __restrict__ mapA,
                                 float* __restrict__ M, float* __restrict__ deg) {
    __shared__ float red[256];
    int m = blockIdx.x, map = blockIdx.y, j = threadIdx.x;
    const float* src = (map == 0) ? supports : mapA;
    float v = 0.f;
    if (j < SENS) {
        float sym = (m >= j) ? src[m * SENS + j] : src[j * SENS + m];
        float a = fabsf(sym);
        v = (a > TH) ? a : 0.f;
        M[(size_t)map * SENS * SENS + m * SENS + j] = v;
    }
    red[j] = v;
    __syncthreads();
    for (int off = 128; off > 0; off >>= 1) {
        if (j < off) red[j] += red[j + off];
        __syncthreads();
    }
    if (j == 0) deg[map * SENS + m] = red[0] + 1.0f;   // + self-loop
}

// ---------------- prep: An bf16 (K-sliced) | weights/bias/bnacc ----------------
// grid 708: [0,448) anbf; [448,708) weights.
__global__ __launch_bounds__(256) void prep2_kernel(
    const float* __restrict__ M, const float* __restrict__ deg,
    const float* __restrict__ W_conv, const float* __restrict__ b_conv,
    const float* __restrict__ W_out,
    __bf16* __restrict__ Anb, __bf16* __restrict__ Wt, __bf16* __restrict__ Wot,
    float* __restrict__ bsum, float* __restrict__ bnacc)
{
    const int bid = blockIdx.x, t = threadIdx.x;
    if (bid < 2 * MPAD) {
        // Anb[map][kc13][m 224][16]
        const int map = bid / MPAD, m = bid % MPAD;
        const int j = t;
        if (j < KP) {
            float val = 0.f;
            if (m < SENS && j < SENS) {
                float a = M[((size_t)map * SENS + m) * SENS + j] + ((m == j) ? 1.f : 0.f);
                val = rsqrtf(deg[map * SENS + m]) * a * rsqrtf(deg[map * SENS + j]);
            }
            Anb[(((size_t)map * 13 + (j >> 4)) * MPAD + m) * 16 + (j & 15)] = (__bf16)val;
        }
    } else {
        const int idx = (bid - 2 * MPAD) * 256 + t;
        if (idx < 32768) {                       // Wt[map][kc8][g128][16] = sum_l W[map][l][f][g]
            const int map = idx >> 14, g = (idx >> 7) & 127, f = idx & 127;
            const float* wp = W_conv + (size_t)map * 2 * DM * DM + f * DM + g;
            Wt[(((size_t)map * 8 + (f >> 4)) * DM + g) * 16 + (f & 15)] = (__bf16)(wp[0] + wp[DM * DM]);
        } else if (idx < 65536) {                // Wot[kc16][d128][16] = W_out[c][d]
            const int k = idx - 32768, d = k >> 8, c = k & 255;
            Wot[(((size_t)(c >> 4)) * DM + d) * 16 + (c & 15)] = (__bf16)W_out[c * DM + d];
        } else if (idx < 65792) {
            const int k = idx - 65536, map = k >> 7, g = k & 127;
            bsum[k] = b_conv[(map * 2) * DM + g] + b_conv[(map * 2 + 1) * DM + g];
        } else if (idx < 66304) {
            bnacc[idx - 65792] = 0.f;
        }
    }
}

// ---------------- x -> xk[bs][kc8][n 224][16] bf16, coalesced reads ----------------
// grid (MPAD, NB): block reads the contiguous [s][f] plane of x[b][n] (48 KB).
__global__ __launch_bounds__(256) void xprep_kernel(const float* __restrict__ x,
                                                    __bf16* __restrict__ xk) {
    const int n = blockIdx.x, b = blockIdx.y, t = threadIdx.x;
    const float* xp = x + ((size_t)b * SENS + n) * SEQ * DM;
    #pragma unroll 4
    for (int it = 0; it < 12; ++it) {
        const int idx = it * 1024 + t * 4;          // element in [0, 12288)
        const int s = idx >> 7, f = idx & 127;
        float4 v = make_float4(0.f, 0.f, 0.f, 0.f);
        if (n < SENS) v = *(const float4*)(xp + idx);
        bf16x4 o;
        o[0] = (__bf16)v.x; o[1] = (__bf16)v.y; o[2] = (__bf16)v.z; o[3] = (__bf16)v.w;
        *(bf16x4*)(xk + (((size_t)(b * SEQ + s) * 8 + (f >> 4)) * MPAD + n) * 16 + (f & 15)) = o;
    }
}

// ---------------- fused conv: xw = Wt@xr^T (LDS), h = An@xw, BN stats ----------------
// grid 3072 = bs*4 + map*2 + gh. 448 threads = 7 waves. Block owns 64 g.
__global__ __launch_bounds__(448, 6) void conv_kernel(
    const __bf16* __restrict__ xk, const __bf16* __restrict__ Anb,
    const __bf16* __restrict__ Wt, const float* __restrict__ bsum,
    __bf16* __restrict__ h, float* __restrict__ bnacc)
{
    __shared__ __bf16 xw[64 * KP];                // 26624 B
    const int bx = blockIdx.x;
    const int bs = bx >> 2, map = (bx >> 1) & 1, gh = bx & 1;
    const int t = threadIdx.x, w = t >> 6, lane = t & 63;
    const int l31 = lane & 31, hi = lane >> 5;

    // ---- phase 1: xw[g 64][n 208] = Wt[g-half] @ xr^T (n-tile = w) ----
    {
        f32x16 acc[2];
        #pragma unroll
        for (int p = 0; p < 2; ++p)
            #pragma unroll
            for (int r = 0; r < 16; ++r) acc[p][r] = 0.f;
        const __bf16* xb = xk + (((size_t)bs * 8) * MPAD + w * 32 + l31) * 16 + hi * 8;
        const __bf16* wb = Wt + (((size_t)map * 8) * DM + gh * 64 + l31) * 16 + hi * 8;
        #pragma unroll
        for (int kh = 0; kh < 2; ++kh) {
            bf16x8 bfr[4];
            #pragma unroll
            for (int q = 0; q < 4; ++q)
                bfr[q] = *(const bf16x8*)(xb + (size_t)(kh * 4 + q) * MPAD * 16);
            #pragma unroll
            for (int q = 0; q < 4; ++q) {
                const __bf16* wp = wb + (size_t)(kh * 4 + q) * DM * 16;
                acc[0] = mfma32(*(const bf16x8*)wp, bfr[q], acc[0]);
                acc[1] = mfma32(*(const bf16x8*)(wp + 32 * 16), bfr[q], acc[1]);
            }
        }
        const int n = w * 32 + l31;
        if (n < KP) {
            #pragma unroll
            for (int p = 0; p < 2; ++p)
                #pragma unroll
                for (int r = 0; r < 16; ++r) {
                    const int g = p * 32 + (r & 3) + 8 * (r >> 2) + 4 * hi;
                    xw[g * KP + n] = (__bf16)acc[p][r];
                }
        }
    }
    __syncthreads();

    // ---- phase 2: h-strip w = An[strip] @ xw^T (K=208), b128 fragment reads ----
    f32x16 acc2[2];
    #pragma unroll
    for (int p = 0; p < 2; ++p)
        #pragma unroll
        for (int r = 0; r < 16; ++r) acc2[p][r] = 0.f;
    {
        const __bf16* ab = Anb + (((size_t)map * 13) * MPAD + w * 32 + l31) * 16 + hi * 8;
        #pragma unroll
        for (int kc = 0; kc < 13; ++kc) {
            bf16x8 afrag = *(const bf16x8*)(ab + (size_t)kc * MPAD * 16);
            #pragma unroll
            for (int p = 0; p < 2; ++p) {
                bf16x8 bfrag = *(const bf16x8*)(xw + (p * 32 + l31) * KP + kc * 16 + hi * 8);
                acc2[p] = mfma32(afrag, bfrag, acc2[p]);
            }
        }
    }
    float bsn[2], bsq[2];
    #pragma unroll
    for (int p = 0; p < 2; ++p) {
        const float bias = bsum[map * DM + gh * 64 + p * 32 + l31];
        bf16x8 h0, h1;
        float s = 0.f, q = 0.f;
        #pragma unroll
        for (int r = 0; r < 16; ++r) {
            const float v = acc2[p][r] + bias;
            if (r < 8) h0[r] = (__bf16)v; else h1[r - 8] = (__bf16)v;
            const int m = w * 32 + (r & 3) + 8 * (r >> 2) + 4 * hi;
            if (m < SENS) { s += v; q += v * v; }
        }
        __bf16* hp = h + ((((size_t)(bs * 2 + map) * 7 + w) * 4 + (gh * 2 + p)) * 64 + lane) * 16;
        *(bf16x8*)hp = h0;
        *(bf16x8*)(hp + 8) = h1;
        s += __shfl_xor(s, 32);
        q += __shfl_xor(q, 32);
        bsn[p] = s; bsq[p] = q;
    }
    __syncthreads();                     // xw reads done; reuse as reduction buffer
    float* red = (float*)xw;             // [2][64][7]
    if (hi == 0) {
        #pragma unroll
        for (int p = 0; p < 2; ++p) {
            red[(p * 32 + l31) * 7 + w] = bsn[p];
            red[(64 + p * 32 + l31) * 7 + w] = bsq[p];
        }
    }
    __syncthreads();
    if (t < 128) {
        const int sq = t >> 6, g = t & 63;
        float s = 0.f;
        #pragma unroll
        for (int k = 0; k < 7; ++k) s += red[(sq * 64 + g) * 7 + k];
        atomicAdd(&bnacc[sq * 256 + map * DM + gh * 64 + g], s);
    }
}

// stage chunk cn of relu(bn(h)) into As buffer (224 rows x 64 cols)
__device__ __forceinline__ void out_stage(int cn, int t, int bs,
                                          const __bf16* __restrict__ h,
                                          const float* sc_s, const float* sh_s,
                                          __bf16* dst)
{
    const int mapn = cn >> 1;
    const __bf16* hb = h + ((size_t)(bs * 2 + mapn) * 28 + (cn & 1) * 2) * 1024;
    bf16x8 vv[4];
    #pragma unroll
    for (int it = 0; it < 4; ++it) {
        const int idx = it * 512 + t;
        if (idx < 1792)
            vv[it] = *(const bf16x8*)(hb + ((size_t)(idx >> 8) * 4 + ((idx >> 7) & 1)) * 1024
                                          + ((idx >> 1) & 63) * 16 + (idx & 1) * 8);
    }
    #pragma unroll
    for (int it = 0; it < 4; ++it) {
        const int idx = it * 512 + t;
        if (idx < 1792) {
            const int half = idx & 1, lane_s = (idx >> 1) & 63;
            const int ctl = (idx >> 7) & 1, strip = idx >> 8;
            const int cl = ctl * 32 + (lane_s & 31);
            const int cg = mapn * DM + (cn & 1) * 64 + cl;
            const float scv = sc_s[cg], shv = sh_s[cg];
            const int mbase = strip * 32 + 4 * (lane_s >> 5) + 16 * half;
            #pragma unroll
            for (int q2 = 0; q2 < 8; ++q2) {
                const int row = mbase + (q2 & 3) + 8 * (q2 >> 2);
                const float fv = (float)vv[it][q2] * scv + shv;
                dst[row * ASROW + cl] = (__bf16)fmaxf(fv, 0.f);
            }
        }
    }
}

// ---------------- out: relu( relu(bn(h)) cat @ W_out + b_out ), double-buffered ----------------
__global__ __launch_bounds__(512) void out_kernel(
    const __bf16* __restrict__ h, const __bf16* __restrict__ Wot,
    const float* __restrict__ bnacc,
    const float* __restrict__ gamma, const float* __restrict__ beta,
    const float* __restrict__ b_out, float* __restrict__ out)
{
    __shared__ __bf16 As[2][MPAD * ASROW];        // 2 x 30464 B
    __shared__ float sc_s[256], sh_s[256];
    const int bs = blockIdx.x;
    const int b = bs / SEQ, s = bs % SEQ;
    const int t = threadIdx.x, w = t >> 6, lane = t & 63;
    const int l31 = lane & 31, hi = lane >> 5;
    const int dct = w & 3, sbase = w >> 2;
    if (t < 256) {                                // BN finalize (fused, per-block)
        const float mu = bnacc[t] * (1.f / (float)NTOT);
        const float var = bnacc[256 + t] * (1.f / (float)NTOT) - mu * mu;
        const float sc = gamma[t] * rsqrtf(var + BN_EPS);
        sc_s[t] = sc;
        sh_s[t] = beta[t] - mu * sc;
    }
    f32x16 acc[4];
    {
        const float bo = b_out[dct * 32 + l31];
        #pragma unroll
        for (int i = 0; i < 4; ++i)
            #pragma unroll
            for (int r = 0; r < 16; ++r) acc[i][r] = bo;
    }
    __syncthreads();
    out_stage(0, t, bs, h, sc_s, sh_s, &As[0][0]);
    __syncthreads();
    for (int c = 0; c < 4; ++c) {
        #pragma unroll
        for (int kc = 0; kc < 4; ++kc) {
            bf16x8 bfrag = *(const bf16x8*)(Wot + ((size_t)(c * 4 + kc) * DM + dct * 32 + l31) * 16 + hi * 8);
            #pragma unroll
            for (int i = 0; i < 4; ++i) {
                const int strip = sbase + 2 * i;
                if (strip >= 7) break;
                const __bf16* ap = &As[c & 1][(strip * 32 + l31) * ASROW + kc * 16 + hi * 8];
                acc[i] = mfma32(join8(*(const bf16x4*)ap, *(const bf16x4*)(ap + 4)), bfrag, acc[i]);
            }
        }
        if (c < 3) out_stage(c + 1, t, bs, h, sc_s, sh_s, &As[(c + 1) & 1][0]);
        __syncthreads();
    }
    #pragma unroll
    for (int i = 0; i < 4; ++i) {
        const int strip = sbase + 2 * i;
        if (strip >= 7) break;
        #pragma unroll
        for (int r = 0; r < 16; ++r) {
            const int m = strip * 32 + (r & 3) + 8 * (r >> 2) + 4 * hi;
            if (m < SENS)
                out[(((size_t)b * SENS + m) * SEQ + s) * DM + dct * 32 + l31] = fmaxf(acc[i][r], 0.f);
        }
    }
}

extern "C" void kernel_launch(void* const* d_in, const int* in_sizes, int n_in,
                              void* d_out, int out_size, void* d_ws, size_t ws_size,
                              hipStream_t stream) {
    const float* x        = (const float*)d_in[0];
    const float* attn     = (const float*)d_in[1];
    const float* supports = (const float*)d_in[2];
    const float* W_conv   = (const float*)d_in[3];
    const float* b_conv   = (const float*)d_in[4];
    const float* gamma    = (const float*)d_in[5];
    const float* beta     = (const float*)d_in[6];
    const float* W_out    = (const float*)d_in[7];
    const float* b_out    = (const float*)d_in[8];
    float* out = (float*)d_out;
    char* base = (char*)d_ws;

    float*  mapA  = (float*)(base + 0);          // 160000
    float*  Mbuf  = (float*)(base + 160000);     // 320000
    float*  deg   = (float*)(base + 480000);     // 1600
    float*  bnacc = (float*)(base + 481664);     // 2048
    float*  bsum  = (float*)(base + 483712);     // 1024
    __bf16* Wt    = (__bf16*)(base + 484736);    // 65536
    __bf16* Wot   = (__bf16*)(base + 550272);    // 65536
    __bf16* Anb   = (__bf16*)(base + 615808);    // 186368
    __bf16* xk    = (__bf16*)(base + 1048576);   // 44040192
    __bf16* h     = (__bf16*)(base + 45088768);  // 88080384 (end ~127 MiB)

    attn_mean_kernel<<<157, 256, 0, stream>>>(attn, mapA);
    build_map_kernel<<<dim3(SENS, 2), 256, 0, stream>>>(supports, mapA, Mbuf, deg);
    prep2_kernel<<<2 * MPAD + 260, 256, 0, stream>>>(Mbuf, deg, W_conv, b_conv, W_out,
                                                     Anb, Wt, Wot, bsum, bnacc);
    xprep_kernel<<<dim3(MPAD, NB), 256, 0, stream>>>(x, xk);
    conv_kernel<<<BS * 4, 448, 0, stream>>>(xk, Anb, Wt, bsum, h, bnacc);
    out_kernel<<<BS, 512, 0, stream>>>(h, Wot, bnacc, gamma, beta, b_out, out);
}

// Round 6
// 274.398 us; speedup vs baseline: 1.0554x; 1.0554x over previous
//
#include <hip/hip_runtime.h>

#define SENS 200
#define DM 128
#define SEQ 96
#define NB 8
#define BS 768            // NB*SEQ
#define NTOT 153600       // BS*SENS
#define TH 0.01f
#define BN_EPS 1e-5f
#define MPAD 224          // padded sensor dim (7*32)
#define KP 208            // effective K for phase2 / xw cols (13*16)
#define XWS 212           // xw LDS row stride (424 B = 106 dw, gcd 2 -> free)
#define ASROW 68          // out As stride (136 B = 34 dw, gcd 2 -> free)

typedef __attribute__((ext_vector_type(8)))  __bf16 bf16x8;
typedef __attribute__((ext_vector_type(4)))  __bf16 bf16x4;
typedef __attribute__((ext_vector_type(16))) float  f32x16;

__device__ __forceinline__ f32x16 mfma32(bf16x8 a, bf16x8 b, f32x16 c) {
    return __builtin_amdgcn_mfma_f32_32x32x16_bf16(a, b, c, 0, 0, 0);
}
__device__ __forceinline__ bf16x8 join8(bf16x4 a, bf16x4 b) {
    bf16x8 r;
    #pragma unroll
    for (int j = 0; j < 4; ++j) { r[j] = a[j]; r[j + 4] = b[j]; }
    return r;
}

// ---------------- mean over 64 attention maps ----------------
__global__ void attn_mean_kernel(const float* __restrict__ attn, float* __restrict__ mapA) {
    int idx = blockIdx.x * 256 + threadIdx.x;
    if (idx >= SENS * SENS) return;
    float s = 0.f;
    #pragma unroll 8
    for (int q = 0; q < 64; ++q) s += attn[(size_t)q * SENS * SENS + idx];
    mapA[idx] = s * (1.0f / 64.0f);
}

// ---------------- symmetrize + clamp + degree ----------------
__global__ void build_map_kernel(const float* __restrict__ supports, const float* __restrict__ mapA,
                                 float* __restrict__ M, float* __restrict__ deg) {
    __shared__ float red[256];
    int m = blockIdx.x, map = blockIdx.y, j = threadIdx.x;
    const float* src = (map == 0) ? supports : mapA;
    float v = 0.f;
    if (j < SENS) {
        float sym = (m >= j) ? src[m * SENS + j] : src[j * SENS + m];
        float a = fabsf(sym);
        v = (a > TH) ? a : 0.f;
        M[(size_t)map * SENS * SENS + m * SENS + j] = v;
    }
    red[j] = v;
    __syncthreads();
    for (int off = 128; off > 0; off >>= 1) {
        if (j < off) red[j] += red[j + off];
        __syncthreads();
    }
    if (j == 0) deg[map * SENS + m] = red[0] + 1.0f;   // + self-loop
}

// ---------------- prep: An bf16 (K-sliced) | weights/bias/bnacc ----------------
__global__ __launch_bounds__(256) void prep2_kernel(
    const float* __restrict__ M, const float* __restrict__ deg,
    const float* __restrict__ W_conv, const float* __restrict__ b_conv,
    const float* __restrict__ W_out,
    __bf16* __restrict__ Anb, __bf16* __restrict__ Wt, __bf16* __restrict__ Wot,
    float* __restrict__ bsum, float* __restrict__ bnacc)
{
    const int bid = blockIdx.x, t = threadIdx.x;
    if (bid < 2 * MPAD) {
        // Anb[map][kc13][m 224][16]
        const int map = bid / MPAD, m = bid % MPAD;
        const int j = t;
        if (j < KP) {
            float val = 0.f;
            if (m < SENS && j < SENS) {
                float a = M[((size_t)map * SENS + m) * SENS + j] + ((m == j) ? 1.f : 0.f);
                val = rsqrtf(deg[map * SENS + m]) * a * rsqrtf(deg[map * SENS + j]);
            }
            Anb[(((size_t)map * 13 + (j >> 4)) * MPAD + m) * 16 + (j & 15)] = (__bf16)val;
        }
    } else {
        const int idx = (bid - 2 * MPAD) * 256 + t;
        if (idx < 32768) {                       // Wt[map][kc8][g128][16] = sum_l W[map][l][f][g]
            const int map = idx >> 14, g = (idx >> 7) & 127, f = idx & 127;
            const float* wp = W_conv + (size_t)map * 2 * DM * DM + f * DM + g;
            Wt[(((size_t)map * 8 + (f >> 4)) * DM + g) * 16 + (f & 15)] = (__bf16)(wp[0] + wp[DM * DM]);
        } else if (idx < 65536) {                // Wot[kc16][d128][16] = W_out[c][d]
            const int k = idx - 32768, d = k >> 8, c = k & 255;
            Wot[(((size_t)(c >> 4)) * DM + d) * 16 + (c & 15)] = (__bf16)W_out[c * DM + d];
        } else if (idx < 65792) {
            const int k = idx - 65536, map = k >> 7, g = k & 127;
            bsum[k] = b_conv[(map * 2) * DM + g] + b_conv[(map * 2 + 1) * DM + g];
        } else if (idx < 66304) {
            bnacc[idx - 65792] = 0.f;
        }
    }
}

// ---------------- fused conv: xw = Wt@xr^T (LDS), h = An@xw, BN stats ----------------
// grid 3072 = bs*4 + map*2 + gh. 448 threads = 7 waves. Block owns 64 g.
// Phase 1 reads x (fp32) directly + converts in-register -- no staging kernel.
__global__ __launch_bounds__(448, 6) void conv_kernel(
    const float* __restrict__ x, const __bf16* __restrict__ Anb,
    const __bf16* __restrict__ Wt, const float* __restrict__ bsum,
    __bf16* __restrict__ h, float* __restrict__ bnacc)
{
    __shared__ __bf16 xw[64 * XWS];               // 27136 B
    const int bx = blockIdx.x;
    const int bs = bx >> 2, map = (bx >> 1) & 1, gh = bx & 1;
    const int b = bs / SEQ, s = bs % SEQ;
    const int t = threadIdx.x, w = t >> 6, lane = t & 63;
    const int l31 = lane & 31, hi = lane >> 5;

    // ---- phase 1: xw[g 64][n 208] = Wt[g-half] @ xr^T (n-tile = w) ----
    {
        f32x16 acc[2];
        #pragma unroll
        for (int p = 0; p < 2; ++p)
            #pragma unroll
            for (int r = 0; r < 16; ++r) acc[p][r] = 0.f;
        const int n = w * 32 + l31;
        const bool valid = (n < SENS);
        const float* xrow = x + (((size_t)b * SENS + (valid ? n : 0)) * SEQ + s) * DM + hi * 8;
        const __bf16* wb = Wt + (((size_t)map * 8) * DM + gh * 64 + l31) * 16 + hi * 8;
        #pragma unroll
        for (int kc = 0; kc < 8; ++kc) {
            float4 v0 = *(const float4*)(xrow + kc * 16);
            float4 v1 = *(const float4*)(xrow + kc * 16 + 4);
            bf16x8 bfrag;
            bfrag[0] = (__bf16)v0.x; bfrag[1] = (__bf16)v0.y;
            bfrag[2] = (__bf16)v0.z; bfrag[3] = (__bf16)v0.w;
            bfrag[4] = (__bf16)v1.x; bfrag[5] = (__bf16)v1.y;
            bfrag[6] = (__bf16)v1.z; bfrag[7] = (__bf16)v1.w;
            if (!valid) {
                #pragma unroll
                for (int j = 0; j < 8; ++j) bfrag[j] = (__bf16)0.f;
            }
            const __bf16* wp = wb + (size_t)kc * DM * 16;
            acc[0] = mfma32(*(const bf16x8*)wp, bfrag, acc[0]);
            acc[1] = mfma32(*(const bf16x8*)(wp + 32 * 16), bfrag, acc[1]);
        }
        if (n < KP) {
            #pragma unroll
            for (int p = 0; p < 2; ++p)
                #pragma unroll
                for (int r = 0; r < 16; ++r) {
                    const int g = p * 32 + (r & 3) + 8 * (r >> 2) + 4 * hi;
                    xw[g * XWS + n] = (__bf16)acc[p][r];
                }
        }
    }
    __syncthreads();

    // ---- phase 2: h-strip w = An[strip] @ xw^T (K=208), b128 fragment reads ----
    f32x16 acc2[2];
    #pragma unroll
    for (int p = 0; p < 2; ++p)
        #pragma unroll
        for (int r = 0; r < 16; ++r) acc2[p][r] = 0.f;
    {
        const __bf16* ab = Anb + (((size_t)map * 13) * MPAD + w * 32 + l31) * 16 + hi * 8;
        #pragma unroll
        for (int kc = 0; kc < 13; ++kc) {
            bf16x8 afrag = *(const bf16x8*)(ab + (size_t)kc * MPAD * 16);
            #pragma unroll
            for (int p = 0; p < 2; ++p) {
                bf16x8 bfrag = *(const bf16x8*)(xw + (p * 32 + l31) * XWS + kc * 16 + hi * 8);
                acc2[p] = mfma32(afrag, bfrag, acc2[p]);
            }
        }
    }
    float bsn[2], bsq[2];
    #pragma unroll
    for (int p = 0; p < 2; ++p) {
        const float bias = bsum[map * DM + gh * 64 + p * 32 + l31];
        bf16x8 h0, h1;
        float s2 = 0.f, q = 0.f;
        #pragma unroll
        for (int r = 0; r < 16; ++r) {
            const float v = acc2[p][r] + bias;
            if (r < 8) h0[r] = (__bf16)v; else h1[r - 8] = (__bf16)v;
            const int m = w * 32 + (r & 3) + 8 * (r >> 2) + 4 * hi;
            if (m < SENS) { s2 += v; q += v * v; }
        }
        __bf16* hp = h + ((((size_t)(bs * 2 + map) * 7 + w) * 4 + (gh * 2 + p)) * 64 + lane) * 16;
        *(bf16x8*)hp = h0;
        *(bf16x8*)(hp + 8) = h1;
        s2 += __shfl_xor(s2, 32);
        q += __shfl_xor(q, 32);
        bsn[p] = s2; bsq[p] = q;
    }
    __syncthreads();                     // xw reads done; reuse as reduction buffer
    float* red = (float*)xw;             // [2][64][7]
    if (hi == 0) {
        #pragma unroll
        for (int p = 0; p < 2; ++p) {
            red[(p * 32 + l31) * 7 + w] = bsn[p];
            red[(64 + p * 32 + l31) * 7 + w] = bsq[p];
        }
    }
    __syncthreads();
    if (t < 128) {
        const int sq = t >> 6, g = t & 63;
        float s2 = 0.f;
        #pragma unroll
        for (int k = 0; k < 7; ++k) s2 += red[(sq * 64 + g) * 7 + k];
        atomicAdd(&bnacc[sq * 256 + map * DM + gh * 64 + g], s2);
    }
}

// stage chunk cn of relu(bn(h)) into As buffer (224 rows x 64 cols)
__device__ __forceinline__ void out_stage(int cn, int t, int bs,
                                          const __bf16* __restrict__ h,
                                          const float* sc_s, const float* sh_s,
                                          __bf16* dst)
{
    const int mapn = cn >> 1;
    const __bf16* hb = h + ((size_t)(bs * 2 + mapn) * 28 + (cn & 1) * 2) * 1024;
    bf16x8 vv[4];
    #pragma unroll
    for (int it = 0; it < 4; ++it) {
        const int idx = it * 512 + t;
        if (idx < 1792)
            vv[it] = *(const bf16x8*)(hb + ((size_t)(idx >> 8) * 4 + ((idx >> 7) & 1)) * 1024
                                          + ((idx >> 1) & 63) * 16 + (idx & 1) * 8);
    }
    #pragma unroll
    for (int it = 0; it < 4; ++it) {
        const int idx = it * 512 + t;
        if (idx < 1792) {
            const int half = idx & 1, lane_s = (idx >> 1) & 63;
            const int ctl = (idx >> 7) & 1, strip = idx >> 8;
            const int cl = ctl * 32 + (lane_s & 31);
            const int cg = mapn * DM + (cn & 1) * 64 + cl;
            const float scv = sc_s[cg], shv = sh_s[cg];
            const int mbase = strip * 32 + 4 * (lane_s >> 5) + 16 * half;
            #pragma unroll
            for (int q2 = 0; q2 < 8; ++q2) {
                const int row = mbase + (q2 & 3) + 8 * (q2 >> 2);
                const float fv = (float)vv[it][q2] * scv + shv;
                dst[row * ASROW + cl] = (__bf16)fmaxf(fv, 0.f);
            }
        }
    }
}

// ---------------- out: relu( relu(bn(h)) cat @ W_out + b_out ), double-buffered ----------------
__global__ __launch_bounds__(512) void out_kernel(
    const __bf16* __restrict__ h, const __bf16* __restrict__ Wot,
    const float* __restrict__ bnacc,
    const float* __restrict__ gamma, const float* __restrict__ beta,
    const float* __restrict__ b_out, float* __restrict__ out)
{
    __shared__ __bf16 As[2][MPAD * ASROW];        // 2 x 30464 B
    __shared__ float sc_s[256], sh_s[256];
    const int bs = blockIdx.x;
    const int b = bs / SEQ, s = bs % SEQ;
    const int t = threadIdx.x, w = t >> 6, lane = t & 63;
    const int l31 = lane & 31, hi = lane >> 5;
    const int dct = w & 3, sbase = w >> 2;
    if (t < 256) {                                // BN finalize (fused, per-block)
        const float mu = bnacc[t] * (1.f / (float)NTOT);
        const float var = bnacc[256 + t] * (1.f / (float)NTOT) - mu * mu;
        const float sc = gamma[t] * rsqrtf(var + BN_EPS);
        sc_s[t] = sc;
        sh_s[t] = beta[t] - mu * sc;
    }
    f32x16 acc[4];
    {
        const float bo = b_out[dct * 32 + l31];
        #pragma unroll
        for (int i = 0; i < 4; ++i)
            #pragma unroll
            for (int r = 0; r < 16; ++r) acc[i][r] = bo;
    }
    __syncthreads();
    out_stage(0, t, bs, h, sc_s, sh_s, &As[0][0]);
    __syncthreads();
    for (int c = 0; c < 4; ++c) {
        #pragma unroll
        for (int kc = 0; kc < 4; ++kc) {
            bf16x8 bfrag = *(const bf16x8*)(Wot + ((size_t)(c * 4 + kc) * DM + dct * 32 + l31) * 16 + hi * 8);
            #pragma unroll
            for (int i = 0; i < 4; ++i) {
                const int strip = sbase + 2 * i;
                if (strip >= 7) break;
                const __bf16* ap = &As[c & 1][(strip * 32 + l31) * ASROW + kc * 16 + hi * 8];
                acc[i] = mfma32(join8(*(const bf16x4*)ap, *(const bf16x4*)(ap + 4)), bfrag, acc[i]);
            }
        }
        if (c < 3) out_stage(c + 1, t, bs, h, sc_s, sh_s, &As[(c + 1) & 1][0]);
        __syncthreads();
    }
    #pragma unroll
    for (int i = 0; i < 4; ++i) {
        const int strip = sbase + 2 * i;
        if (strip >= 7) break;
        #pragma unroll
        for (int r = 0; r < 16; ++r) {
            const int m = strip * 32 + (r & 3) + 8 * (r >> 2) + 4 * hi;
            if (m < SENS)
                out[(((size_t)b * SENS + m) * SEQ + s) * DM + dct * 32 + l31] = fmaxf(acc[i][r], 0.f);
        }
    }
}

extern "C" void kernel_launch(void* const* d_in, const int* in_sizes, int n_in,
                              void* d_out, int out_size, void* d_ws, size_t ws_size,
                              hipStream_t stream) {
    const float* x        = (const float*)d_in[0];
    const float* attn     = (const float*)d_in[1];
    const float* supports = (const float*)d_in[2];
    const float* W_conv   = (const float*)d_in[3];
    const float* b_conv   = (const float*)d_in[4];
    const float* gamma    = (const float*)d_in[5];
    const float* beta     = (const float*)d_in[6];
    const float* W_out    = (const float*)d_in[7];
    const float* b_out    = (const float*)d_in[8];
    float* out = (float*)d_out;
    char* base = (char*)d_ws;

    float*  mapA  = (float*)(base + 0);          // 160000
    float*  Mbuf  = (float*)(base + 160000);     // 320000
    float*  deg   = (float*)(base + 480000);     // 1600
    float*  bnacc = (float*)(base + 481664);     // 2048
    float*  bsum  = (float*)(base + 483712);     // 1024
    __bf16* Wt    = (__bf16*)(base + 484736);    // 65536
    __bf16* Wot   = (__bf16*)(base + 550272);    // 65536
    __bf16* Anb   = (__bf16*)(base + 615808);    // 186368
    __bf16* h     = (__bf16*)(base + 1048576);   // 88080384 (end ~85 MiB)

    attn_mean_kernel<<<157, 256, 0, stream>>>(attn, mapA);
    build_map_kernel<<<dim3(SENS, 2), 256, 0, stream>>>(supports, mapA, Mbuf, deg);
    prep2_kernel<<<2 * MPAD + 260, 256, 0, stream>>>(Mbuf, deg, W_conv, b_conv, W_out,
                                                     Anb, Wt, Wot, bsum, bnacc);
    conv_kernel<<<BS * 4, 448, 0, stream>>>(x, Anb, Wt, bsum, h, bnacc);
    out_kernel<<<BS, 512, 0, stream>>>(h, Wot, bnacc, gamma, beta, b_out, out);
}

// Round 7
// 261.299 us; speedup vs baseline: 1.1083x; 1.0501x over previous
//
#include <hip/hip_runtime.h>

#define SENS 200
#define DM 128
#define SEQ 96
#define NB 8
#define BS 768            // NB*SEQ
#define NTOT 153600       // BS*SENS
#define TH 0.01f
#define BN_EPS 1e-5f
#define MPAD 224          // padded sensor dim (7*32)
#define KP 208            // effective K for phase2 / xw cols (13*16)
#define XWS 212           // xw LDS row stride (424 B = 106 dw, gcd 2 -> free)
#define ASROW 68          // out As stride (136 B = 34 dw, gcd 2 -> free)

typedef __attribute__((ext_vector_type(8)))  __bf16 bf16x8;
typedef __attribute__((ext_vector_type(4)))  __bf16 bf16x4;
typedef __attribute__((ext_vector_type(16))) float  f32x16;

__device__ __forceinline__ f32x16 mfma32(bf16x8 a, bf16x8 b, f32x16 c) {
    return __builtin_amdgcn_mfma_f32_32x32x16_bf16(a, b, c, 0, 0, 0);
}
__device__ __forceinline__ bf16x8 join8(bf16x4 a, bf16x4 b) {
    bf16x8 r;
    #pragma unroll
    for (int j = 0; j < 4; ++j) { r[j] = a[j]; r[j + 4] = b[j]; }
    return r;
}

// ---------------- mean over 64 attention maps ----------------
__global__ void attn_mean_kernel(const float* __restrict__ attn, float* __restrict__ mapA) {
    int idx = blockIdx.x * 256 + threadIdx.x;
    if (idx >= SENS * SENS) return;
    float s = 0.f;
    #pragma unroll 8
    for (int q = 0; q < 64; ++q) s += attn[(size_t)q * SENS * SENS + idx];
    mapA[idx] = s * (1.0f / 64.0f);
}

// ---------------- symmetrize + clamp + degree ----------------
__global__ void build_map_kernel(const float* __restrict__ supports, const float* __restrict__ mapA,
                                 float* __restrict__ M, float* __restrict__ deg) {
    __shared__ float red[256];
    int m = blockIdx.x, map = blockIdx.y, j = threadIdx.x;
    const float* src = (map == 0) ? supports : mapA;
    float v = 0.f;
    if (j < SENS) {
        float sym = (m >= j) ? src[m * SENS + j] : src[j * SENS + m];
        float a = fabsf(sym);
        v = (a > TH) ? a : 0.f;
        M[(size_t)map * SENS * SENS + m * SENS + j] = v;
    }
    red[j] = v;
    __syncthreads();
    for (int off = 128; off > 0; off >>= 1) {
        if (j < off) red[j] += red[j + off];
        __syncthreads();
    }
    if (j == 0) deg[map * SENS + m] = red[0] + 1.0f;   // + self-loop
}

// ---------------- prep: An bf16 (K-sliced) | weights/bias/bnacc ----------------
__global__ __launch_bounds__(256) void prep2_kernel(
    const float* __restrict__ M, const float* __restrict__ deg,
    const float* __restrict__ W_conv, const float* __restrict__ b_conv,
    const float* __restrict__ W_out,
    __bf16* __restrict__ Anb, __bf16* __restrict__ Wt, __bf16* __restrict__ Wot,
    float* __restrict__ bsum, float* __restrict__ bnacc)
{
    const int bid = blockIdx.x, t = threadIdx.x;
    if (bid < 2 * MPAD) {
        // Anb[map][kc13][m 224][16]
        const int map = bid / MPAD, m = bid % MPAD;
        const int j = t;
        if (j < KP) {
            float val = 0.f;
            if (m < SENS && j < SENS) {
                float a = M[((size_t)map * SENS + m) * SENS + j] + ((m == j) ? 1.f : 0.f);
                val = rsqrtf(deg[map * SENS + m]) * a * rsqrtf(deg[map * SENS + j]);
            }
            Anb[(((size_t)map * 13 + (j >> 4)) * MPAD + m) * 16 + (j & 15)] = (__bf16)val;
        }
    } else {
        const int idx = (bid - 2 * MPAD) * 256 + t;
        if (idx < 32768) {                       // Wt[map][kc8][g128][16] = sum_l W[map][l][f][g]
            const int map = idx >> 14, g = (idx >> 7) & 127, f = idx & 127;
            const float* wp = W_conv + (size_t)map * 2 * DM * DM + f * DM + g;
            Wt[(((size_t)map * 8 + (f >> 4)) * DM + g) * 16 + (f & 15)] = (__bf16)(wp[0] + wp[DM * DM]);
        } else if (idx < 65536) {                // Wot[kc16][d128][16] = W_out[c][d]
            const int k = idx - 32768, d = k >> 8, c = k & 255;
            Wot[(((size_t)(c >> 4)) * DM + d) * 16 + (c & 15)] = (__bf16)W_out[c * DM + d];
        } else if (idx < 65792) {
            const int k = idx - 65536, map = k >> 7, g = k & 127;
            bsum[k] = b_conv[(map * 2) * DM + g] + b_conv[(map * 2 + 1) * DM + g];
        } else if (idx < 66304) {
            bnacc[idx - 65792] = 0.f;
        }
    }
}

// ---------------- fused conv: one block per bs, both maps, full g=128 ----------------
// 448 threads = 7 waves. p1: wave = n-tile (4 g-tiles). p2: wave = m-strip (4 g-tiles).
// x is read by exactly this block (map-1 pass re-hits L1/L2).
__global__ __launch_bounds__(448, 4) void conv_kernel(
    const float* __restrict__ x, const __bf16* __restrict__ Anb,
    const __bf16* __restrict__ Wt, const float* __restrict__ bsum,
    __bf16* __restrict__ h, float* __restrict__ bnacc)
{
    __shared__ __bf16 xw[128 * XWS];              // 54272 B -> 2 blocks/CU
    const int bs = blockIdx.x;
    const int b = bs / SEQ, s = bs % SEQ;
    const int t = threadIdx.x, w = t >> 6, lane = t & 63;
    const int l31 = lane & 31, hi = lane >> 5;

    const int n = w * 32 + l31;
    const bool valid = (n < SENS);
    const float* xrow = x + (((size_t)b * SENS + (valid ? n : 0)) * SEQ + s) * DM + hi * 8;

    float bsn[2][4], bsq[2][4];

    #pragma unroll 1
    for (int map = 0; map < 2; ++map) {
        if (map) __syncthreads();                 // p2(map-1) readers done before rewrite
        // ---- phase 1: xw[g 128][n 208] = Wt[map] @ xr^T (n-tile = w) ----
        {
            f32x16 acc[4];
            #pragma unroll
            for (int gt = 0; gt < 4; ++gt)
                #pragma unroll
                for (int r = 0; r < 16; ++r) acc[gt][r] = 0.f;
            const __bf16* wb = Wt + (((size_t)map * 8) * DM + l31) * 16 + hi * 8;
            #pragma unroll
            for (int kc = 0; kc < 8; ++kc) {
                float4 v0 = *(const float4*)(xrow + kc * 16);
                float4 v1 = *(const float4*)(xrow + kc * 16 + 4);
                bf16x8 bfrag;
                bfrag[0] = (__bf16)v0.x; bfrag[1] = (__bf16)v0.y;
                bfrag[2] = (__bf16)v0.z; bfrag[3] = (__bf16)v0.w;
                bfrag[4] = (__bf16)v1.x; bfrag[5] = (__bf16)v1.y;
                bfrag[6] = (__bf16)v1.z; bfrag[7] = (__bf16)v1.w;
                if (!valid) {
                    #pragma unroll
                    for (int j = 0; j < 8; ++j) bfrag[j] = (__bf16)0.f;
                }
                const __bf16* wp = wb + (size_t)kc * DM * 16;
                #pragma unroll
                for (int gt = 0; gt < 4; ++gt)
                    acc[gt] = mfma32(*(const bf16x8*)(wp + gt * 32 * 16), bfrag, acc[gt]);
            }
            if (n < KP) {
                #pragma unroll
                for (int gt = 0; gt < 4; ++gt)
                    #pragma unroll
                    for (int r = 0; r < 16; ++r) {
                        const int g = gt * 32 + (r & 3) + 8 * (r >> 2) + 4 * hi;
                        xw[g * XWS + n] = (__bf16)acc[gt][r];
                    }
            }
        }
        __syncthreads();

        // ---- phase 2: h-strip w = An[strip] @ xw^T (K=208) ----
        f32x16 acc2[4];
        #pragma unroll
        for (int gt = 0; gt < 4; ++gt)
            #pragma unroll
            for (int r = 0; r < 16; ++r) acc2[gt][r] = 0.f;
        {
            const __bf16* ab = Anb + (((size_t)map * 13) * MPAD + w * 32 + l31) * 16 + hi * 8;
            #pragma unroll 2
            for (int kc = 0; kc < 13; ++kc) {
                bf16x8 afrag = *(const bf16x8*)(ab + (size_t)kc * MPAD * 16);
                #pragma unroll
                for (int gt = 0; gt < 4; ++gt) {
                    bf16x8 bfrag = *(const bf16x8*)(xw + (gt * 32 + l31) * XWS + kc * 16 + hi * 8);
                    acc2[gt] = mfma32(afrag, bfrag, acc2[gt]);
                }
            }
        }
        #pragma unroll
        for (int gt = 0; gt < 4; ++gt) {
            const float bias = bsum[map * DM + gt * 32 + l31];
            bf16x8 h0, h1;
            float s2 = 0.f, q = 0.f;
            #pragma unroll
            for (int r = 0; r < 16; ++r) {
                const float v = acc2[gt][r] + bias;
                if (r < 8) h0[r] = (__bf16)v; else h1[r - 8] = (__bf16)v;
                const int m = w * 32 + (r & 3) + 8 * (r >> 2) + 4 * hi;
                if (m < SENS) { s2 += v; q += v * v; }
            }
            __bf16* hp = h + ((((size_t)(bs * 2 + map) * 7 + w) * 4 + gt) * 64 + lane) * 16;
            *(bf16x8*)hp = h0;
            *(bf16x8*)(hp + 8) = h1;
            s2 += __shfl_xor(s2, 32);
            q += __shfl_xor(q, 32);
            bsn[map][gt] = s2; bsq[map][gt] = q;
        }
    }
    __syncthreads();                     // xw reads done; reuse as reduction buffer
    float* red = (float*)xw;             // [2 map][2 sq][128 g][7 w] = 14336 B
    if (hi == 0) {
        #pragma unroll
        for (int map = 0; map < 2; ++map)
            #pragma unroll
            for (int gt = 0; gt < 4; ++gt) {
                red[(((map * 2 + 0) * 128) + gt * 32 + l31) * 7 + w] = bsn[map][gt];
                red[(((map * 2 + 1) * 128) + gt * 32 + l31) * 7 + w] = bsq[map][gt];
            }
    }
    __syncthreads();
    for (int i = t; i < 512; i += 448) {
        const int map = i >> 8, sq = (i >> 7) & 1, g = i & 127;
        float s2 = 0.f;
        #pragma unroll
        for (int k = 0; k < 7; ++k) s2 += red[i * 7 + k];
        atomicAdd(&bnacc[sq * 256 + map * DM + g], s2);
    }
}

// stage chunk cn of relu(bn(h)) into As buffer (224 rows x 64 cols)
__device__ __forceinline__ void out_stage(int cn, int t, int bs,
                                          const __bf16* __restrict__ h,
                                          const float* sc_s, const float* sh_s,
                                          __bf16* dst)
{
    const int mapn = cn >> 1;
    const __bf16* hb = h + ((size_t)(bs * 2 + mapn) * 28 + (cn & 1) * 2) * 1024;
    bf16x8 vv[4];
    #pragma unroll
    for (int it = 0; it < 4; ++it) {
        const int idx = it * 512 + t;
        if (idx < 1792)
            vv[it] = *(const bf16x8*)(hb + ((size_t)(idx >> 8) * 4 + ((idx >> 7) & 1)) * 1024
                                          + ((idx >> 1) & 63) * 16 + (idx & 1) * 8);
    }
    #pragma unroll
    for (int it = 0; it < 4; ++it) {
        const int idx = it * 512 + t;
        if (idx < 1792) {
            const int half = idx & 1, lane_s = (idx >> 1) & 63;
            const int ctl = (idx >> 7) & 1, strip = idx >> 8;
            const int cl = ctl * 32 + (lane_s & 31);
            const int cg = mapn * DM + (cn & 1) * 64 + cl;
            const float scv = sc_s[cg], shv = sh_s[cg];
            const int mbase = strip * 32 + 4 * (lane_s >> 5) + 16 * half;
            #pragma unroll
            for (int q2 = 0; q2 < 8; ++q2) {
                const int row = mbase + (q2 & 3) + 8 * (q2 >> 2);
                const float fv = (float)vv[it][q2] * scv + shv;
                dst[row * ASROW + cl] = (__bf16)fmaxf(fv, 0.f);
            }
        }
    }
}

// ---------------- out: relu( relu(bn(h)) cat @ W_out + b_out ), double-buffered ----------------
__global__ __launch_bounds__(512) void out_kernel(
    const __bf16* __restrict__ h, const __bf16* __restrict__ Wot,
    const float* __restrict__ bnacc,
    const float* __restrict__ gamma, const float* __restrict__ beta,
    const float* __restrict__ b_out, float* __restrict__ out)
{
    __shared__ __bf16 As[2][MPAD * ASROW];        // 2 x 30464 B
    __shared__ float sc_s[256], sh_s[256];
    const int bs = blockIdx.x;
    const int b = bs / SEQ, s = bs % SEQ;
    const int t = threadIdx.x, w = t >> 6, lane = t & 63;
    const int l31 = lane & 31, hi = lane >> 5;
    const int dct = w & 3, sbase = w >> 2;
    if (t < 256) {                                // BN finalize (fused, per-block)
        const float mu = bnacc[t] * (1.f / (float)NTOT);
        const float var = bnacc[256 + t] * (1.f / (float)NTOT) - mu * mu;
        const float sc = gamma[t] * rsqrtf(var + BN_EPS);
        sc_s[t] = sc;
        sh_s[t] = beta[t] - mu * sc;
    }
    f32x16 acc[4];
    {
        const float bo = b_out[dct * 32 + l31];
        #pragma unroll
        for (int i = 0; i < 4; ++i)
            #pragma unroll
            for (int r = 0; r < 16; ++r) acc[i][r] = bo;
    }
    __syncthreads();
    out_stage(0, t, bs, h, sc_s, sh_s, &As[0][0]);
    __syncthreads();
    for (int c = 0; c < 4; ++c) {
        #pragma unroll
        for (int kc = 0; kc < 4; ++kc) {
            bf16x8 bfrag = *(const bf16x8*)(Wot + ((size_t)(c * 4 + kc) * DM + dct * 32 + l31) * 16 + hi * 8);
            #pragma unroll
            for (int i = 0; i < 4; ++i) {
                const int strip = sbase + 2 * i;
                if (strip >= 7) break;
                const __bf16* ap = &As[c & 1][(strip * 32 + l31) * ASROW + kc * 16 + hi * 8];
                acc[i] = mfma32(join8(*(const bf16x4*)ap, *(const bf16x4*)(ap + 4)), bfrag, acc[i]);
            }
        }
        if (c < 3) out_stage(c + 1, t, bs, h, sc_s, sh_s, &As[(c + 1) & 1][0]);
        __syncthreads();
    }
    #pragma unroll
    for (int i = 0; i < 4; ++i) {
        const int strip = sbase + 2 * i;
        if (strip >= 7) break;
        #pragma unroll
        for (int r = 0; r < 16; ++r) {
            const int m = strip * 32 + (r & 3) + 8 * (r >> 2) + 4 * hi;
            if (m < SENS)
                out[(((size_t)b * SENS + m) * SEQ + s) * DM + dct * 32 + l31] = fmaxf(acc[i][r], 0.f);
        }
    }
}

extern "C" void kernel_launch(void* const* d_in, const int* in_sizes, int n_in,
                              void* d_out, int out_size, void* d_ws, size_t ws_size,
                              hipStream_t stream) {
    const float* x        = (const float*)d_in[0];
    const float* attn     = (const float*)d_in[1];
    const float* supports = (const float*)d_in[2];
    const float* W_conv   = (const float*)d_in[3];
    const float* b_conv   = (const float*)d_in[4];
    const float* gamma    = (const float*)d_in[5];
    const float* beta     = (const float*)d_in[6];
    const float* W_out    = (const float*)d_in[7];
    const float* b_out    = (const float*)d_in[8];
    float* out = (float*)d_out;
    char* base = (char*)d_ws;

    float*  mapA  = (float*)(base + 0);          // 160000
    float*  Mbuf  = (float*)(base + 160000);     // 320000
    float*  deg   = (float*)(base + 480000);     // 1600
    float*  bnacc = (float*)(base + 481664);     // 2048
    float*  bsum  = (float*)(base + 483712);     // 1024
    __bf16* Wt    = (__bf16*)(base + 484736);    // 65536
    __bf16* Wot   = (__bf16*)(base + 550272);    // 65536
    __bf16* Anb   = (__bf16*)(base + 615808);    // 186368
    __bf16* h     = (__bf16*)(base + 1048576);   // 88080384 (end ~85 MiB)

    attn_mean_kernel<<<157, 256, 0, stream>>>(attn, mapA);
    build_map_kernel<<<dim3(SENS, 2), 256, 0, stream>>>(supports, mapA, Mbuf, deg);
    prep2_kernel<<<2 * MPAD + 260, 256, 0, stream>>>(Mbuf, deg, W_conv, b_conv, W_out,
                                                     Anb, Wt, Wot, bsum, bnacc);
    conv_kernel<<<BS, 448, 0, stream>>>(x, Anb, Wt, bsum, h, bnacc);
    out_kernel<<<BS, 512, 0, stream>>>(h, Wot, bnacc, gamma, beta, b_out, out);
}